// Round 1
// baseline (2856.848 us; speedup 1.0000x reference)
//
#include <hip/hip_runtime.h>
#include <math.h>

#define CI   256
#define CO   256
#define HW   56
#define LQ   7
#define BETA 10.0f
#define COT  8   // co per block

// ---------------- Kernel 1: soft-quantize weights ----------------
// conv_w[o,i,kh,kw] = sum_l softmax_l(BETA * p/||p||_2)[l] * q_level[l]
__global__ void quant_weights(const float* __restrict__ p_c,
                              const float* __restrict__ q_level,
                              float* __restrict__ w, int n) {
    int idx = blockIdx.x * blockDim.x + threadIdx.x;
    if (idx >= n) return;
    const float* p = p_c + (size_t)idx * LQ;
    float pv[LQ];
    float ss = 0.f;
#pragma unroll
    for (int l = 0; l < LQ; ++l) { pv[l] = p[l]; ss += pv[l] * pv[l]; }
    float inv = rsqrtf(ss) * BETA;
    float m = -1e30f;
#pragma unroll
    for (int l = 0; l < LQ; ++l) { pv[l] *= inv; m = fmaxf(m, pv[l]); }
    float den = 0.f, num = 0.f;
#pragma unroll
    for (int l = 0; l < LQ; ++l) {
        float e = expf(pv[l] - m);
        den += e;
        num += e * q_level[l];
    }
    w[idx] = num / den;
}

// ---------------- Kernel 2: direct 3x3 conv, f32 ----------------
// block: 256 threads = 4 rows x 64 lanes (56 active)
// block tile: (b, 8 co, 4 h rows, all 56 w)
// per ci: x halo tile (6x58) staged in LDS; weights read with wave-uniform
// addresses -> compiler emits scalar loads (SGPR operands for the FMAs).
__global__ __launch_bounds__(256) void conv3x3(const float* __restrict__ x,
                                               const float* __restrict__ w,
                                               float* __restrict__ out) {
    __shared__ float xt[6 * 64];  // 6 rows x 58 cols (padded to 64)

    const int tid   = threadIdx.x;
    const int wlane = tid & 63;       // output column
    const int hloc  = tid >> 6;       // 0..3 output row within tile
    const int h0    = blockIdx.x * 4; // 14 tiles cover 56 rows exactly
    const int co0   = blockIdx.y * COT;
    const int b     = blockIdx.z;

    float acc[COT];
#pragma unroll
    for (int i = 0; i < COT; ++i) acc[i] = 0.f;

    const float* xb = x + (size_t)b * CI * HW * HW;

    for (int ci = 0; ci < CI; ++ci) {
        // ---- stage x tile: rows h0-1..h0+4, cols -1..56 (zero padded) ----
        const float* xp = xb + (size_t)ci * HW * HW;
        for (int li = tid; li < 6 * 58; li += 256) {
            int row = li / 58, col = li % 58;
            int gr = h0 - 1 + row, gc = col - 1;
            float v = 0.f;
            if (gr >= 0 && gr < HW && gc >= 0 && gc < HW) v = xp[gr * HW + gc];
            xt[row * 64 + col] = v;
        }
        __syncthreads();

        if (wlane < HW) {
            float xr[9];
#pragma unroll
            for (int i = 0; i < 3; ++i)
#pragma unroll
                for (int j = 0; j < 3; ++j)
                    xr[i * 3 + j] = xt[(hloc + i) * 64 + wlane + j];

            // weights: wave-uniform address -> scalar loads
            const float* wg = w + ((size_t)co0 * CI + ci) * 9;
#pragma unroll
            for (int oc = 0; oc < COT; ++oc) {
                const float* wr = wg + (size_t)oc * CI * 9;
                float a = acc[oc];
#pragma unroll
                for (int k = 0; k < 9; ++k)
                    a = fmaf(xr[k], wr[k], a);
                acc[oc] = a;
            }
        }
        __syncthreads();
    }

    if (wlane < HW) {
        int h = h0 + hloc;
#pragma unroll
        for (int oc = 0; oc < COT; ++oc)
            out[(((size_t)b * CO + co0 + oc) * HW + h) * HW + wlane] = acc[oc];
    }
}

extern "C" void kernel_launch(void* const* d_in, const int* in_sizes, int n_in,
                              void* d_out, int out_size, void* d_ws, size_t ws_size,
                              hipStream_t stream) {
    const float* x       = (const float*)d_in[0]; // (32,256,56,56)
    const float* p_c     = (const float*)d_in[1]; // (256,256,3,3,7)
    const float* q_level = (const float*)d_in[2]; // (7,)
    float* out = (float*)d_out;                   // (32,256,56,56)
    float* w   = (float*)d_ws;                    // (256,256,3,3) = 2.36 MB

    const int nW = CO * CI * 9;
    quant_weights<<<(nW + 255) / 256, 256, 0, stream>>>(p_c, q_level, w, nW);

    dim3 grid(HW / 4, CO / COT, 32);  // (14, 32, 32)
    conv3x3<<<grid, 256, 0, stream>>>(x, w, out);
}

// Round 2
// 166.036 us; speedup vs baseline: 17.2061x; 17.2061x over previous
//
#include <hip/hip_runtime.h>
#include <math.h>

#define CI   256
#define CO   256
#define HW   56
#define LQ   7
#define BETA 10.0f

typedef __attribute__((ext_vector_type(8))) short short8;
typedef __attribute__((ext_vector_type(4))) float f32x4;

__device__ __forceinline__ ushort f2bf(float f) {
    // round-to-nearest-even f32 -> bf16 (inputs are finite normals)
    uint u = __float_as_uint(f);
    u += 0x7FFF + ((u >> 16) & 1);
    return (ushort)(u >> 16);
}

// ---------------- Kernel 1: soft-quantize weights -> packed bf16 ----------------
// W2 layout: [chunk 8][tap 9][kb 4][co 256][e 8] bf16  (k = chunk*32 + kb*8 + e)
__global__ void quant_weights(const float* __restrict__ p_c,
                              const float* __restrict__ q_level,
                              short* __restrict__ W2) {
    int idx = blockIdx.x * blockDim.x + threadIdx.x;  // (co, ci)
    if (idx >= CO * CI) return;
    int co = idx >> 8, ci = idx & 255;
    float ql[LQ];
#pragma unroll
    for (int l = 0; l < LQ; ++l) ql[l] = q_level[l];
    const float* p = p_c + (size_t)idx * 9 * LQ;  // [co][ci][kh][kw][l]
#pragma unroll
    for (int t = 0; t < 9; ++t) {
        float pv[LQ];
        float ss = 0.f;
#pragma unroll
        for (int l = 0; l < LQ; ++l) { pv[l] = p[t * LQ + l]; ss += pv[l] * pv[l]; }
        float inv = rsqrtf(ss) * BETA;
        float m = -1e30f;
#pragma unroll
        for (int l = 0; l < LQ; ++l) { pv[l] *= inv; m = fmaxf(m, pv[l]); }
        float den = 0.f, num = 0.f;
#pragma unroll
        for (int l = 0; l < LQ; ++l) {
            float e = expf(pv[l] - m);
            den += e;
            num += e * ql[l];
        }
        float val = num / den;
        int widx = ((((ci >> 5) * 9 + t) * 4 + ((ci >> 3) & 3)) * 2048) + co * 8 + (ci & 7);
        W2[widx] = (short)f2bf(val);
    }
}

// ---------------- Kernel 2: implicit-GEMM 3x3 conv, bf16 MFMA ----------------
// block: 256 thr = 4 waves; tile M=128 co x N=256 (4 h-rows x 64 w, w>=56 masked)
// wave tile: 64 co x 128 n (2 rows x 64 w)
// LDS x tile: rows 0..5 (h0-1..h0+4), cols 0..65 (w-1..w+64), 32 ci, ci-minor,
// swizzle kb' = kb ^ ((c>>1)&3) -> conflict-free b128 reads/writes,
// invariant under c+16 and r+1 (72*32 elems, 72%8==0).
__global__ __launch_bounds__(256, 2) void conv_mfma(const float* __restrict__ x,
                                                    const short* __restrict__ W2,
                                                    float* __restrict__ out) {
    __shared__ __align__(16) short xt[6 * 72 * 32];  // 27648 B

    const int tid  = threadIdx.x;
    const int lane = tid & 63;
    const int wv   = tid >> 6;
    const int l15  = lane & 15;
    const int kb   = lane >> 4;
    const int wm    = (wv >> 1) * 64;  // wave co offset in block
    const int wnrow = (wv & 1) * 2;    // wave row offset (of 4)

    const int h0  = blockIdx.x * 4;
    const int co0 = blockIdx.y * 128;
    const int b   = blockIdx.z;

    f32x4 acc[4][8];
#pragma unroll
    for (int a = 0; a < 4; ++a)
#pragma unroll
        for (int f = 0; f < 8; ++f) acc[a][f] = (f32x4){0.f, 0.f, 0.f, 0.f};

    const float* xb = x + (size_t)b * CI * HW * HW;

    for (int ch = 0; ch < 8; ++ch) {
        const int ci0 = ch * 32;
        // ---- stage: transpose (w-contig global) -> (ci-minor LDS), f32->bf16 ----
        for (int f = tid; f < 6 * 66; f += 256) {
            int r = f / 66, c = f % 66;
            int h = h0 - 1 + r, wc = c - 1;
            bool valid = (h >= 0) & (h < HW) & (wc >= 0) & (wc < HW);
            const float* xs = xb + (size_t)ci0 * 3136 + (valid ? (h * HW + wc) : 0);
            int sw = (c >> 1) & 3;
            int sbase = (r * 72 + c) * 32;
#pragma unroll
            for (int k = 0; k < 4; ++k) {
                short8 pk;
#pragma unroll
                for (int e = 0; e < 8; ++e) {
                    float v = xs[(size_t)(k * 8 + e) * 3136];
                    pk[e] = (short)f2bf(valid ? v : 0.f);
                }
                *(short8*)&xt[sbase + ((k ^ sw) * 8)] = pk;
            }
        }
        __syncthreads();

        // ---- compute: 9 taps x (4 A-frags global, 8 B-frags LDS, 32 MFMA) ----
#pragma unroll
        for (int kh = 0; kh < 3; ++kh) {
#pragma unroll
            for (int kw = 0; kw < 3; ++kw) {
                const int t = kh * 3 + kw;
                const short* ap = W2 + (size_t)((((ch * 9 + t) * 4 + kb) * 256) + co0 + wm + l15) * 8;
                short8 af[4];
#pragma unroll
                for (int a = 0; a < 4; ++a) af[a] = *(const short8*)(ap + a * 128);

                const int c0 = kw + l15;
                const int r0 = wnrow + kh;
                const short* bp = &xt[(r0 * 72 + c0) * 32 + ((kb ^ ((c0 >> 1) & 3)) * 8)];
                short8 bf[8];
#pragma unroll
                for (int f = 0; f < 8; ++f)
                    bf[f] = *(const short8*)(bp + (f >> 2) * 2304 + (f & 3) * 512);

#pragma unroll
                for (int a = 0; a < 4; ++a)
#pragma unroll
                    for (int f = 0; f < 8; ++f)
                        acc[a][f] = __builtin_amdgcn_mfma_f32_16x16x32_bf16(af[a], bf[f], acc[a][f], 0, 0, 0);
            }
        }
        __syncthreads();
    }

    // ---- epilogue: D layout n=lane&15, m=(lane>>4)*4+j ----
#pragma unroll
    for (int a = 0; a < 4; ++a) {
#pragma unroll
        for (int f = 0; f < 8; ++f) {
            int wloc = (f & 3) * 16 + l15;
            if (wloc < HW) {
                int h = h0 + wnrow + (f >> 2);
#pragma unroll
                for (int j = 0; j < 4; ++j) {
                    int cog = co0 + wm + 16 * a + kb * 4 + j;
                    out[(((size_t)b * CO + cog) * HW + h) * HW + wloc] = acc[a][f][j];
                }
            }
        }
    }
}

extern "C" void kernel_launch(void* const* d_in, const int* in_sizes, int n_in,
                              void* d_out, int out_size, void* d_ws, size_t ws_size,
                              hipStream_t stream) {
    const float* x       = (const float*)d_in[0]; // (32,256,56,56)
    const float* p_c     = (const float*)d_in[1]; // (256,256,3,3,7)
    const float* q_level = (const float*)d_in[2]; // (7,)
    float* out = (float*)d_out;                   // (32,256,56,56)
    short* W2  = (short*)d_ws;                    // packed bf16 weights, 1.18 MB

    quant_weights<<<(CO * CI + 255) / 256, 256, 0, stream>>>(p_c, q_level, W2);

    dim3 grid(HW / 4, CO / 128, 32);  // (14, 2, 32) = 896 blocks
    conv_mfma<<<grid, 256, 0, stream>>>(x, W2, out);
}